// Round 4
// baseline (317.076 us; speedup 1.0000x reference)
//
#include <hip/hip_runtime.h>

#define B_SZ   32
#define LEN    2048
#define DIM    256
#define NST    64
#define OUTD   256
#define CHUNK  64
#define NCHUNK (LEN / CHUNK)     // 32
#define ROWS   (B_SZ * LEN)      // 65536

// ws layout (float offsets)
#define OFF_AT   0               // A_tilde [64][64]
#define OFF_A64  4096            // A_tilde^64 [64][64]
#define OFF_BT   8192            // BTt[d][n] = dt*(Minv@B)[n][d], [256][64]
#define OFF_CT   24576           // CT[n][o] = C[o][n], [64][256]
#define OFF_S    40960           // chunk states [B][NCHUNK][64]; carry overwrites in place
#define OFF_U    106496          // u = x @ BTt  [ROWS][64]
#define OFF_H    4300800         // h states [ROWS][64]
#define WS_FLOATS (OFF_H + ROWS * 64)   // 8,495,104 floats = 34.0 MiB

// ---------------------------------------------------------------------------
// K1 prep (1 block, 256 thr): GJ inverse of M = I + (dt/2)A (1 barrier/iter,
// register-resident); At = 2*Minv - I; BTt[d][n] = dt*(Minv@B)^T; A64 = At^64
// (6 squarings); CT = C^T. All LDS access broadcast or stride-1/65 (2-way).
// ---------------------------------------------------------------------------
__global__ __launch_bounds__(256) void k_prep(const float* __restrict__ A,
                                              const float* __restrict__ Bm,
                                              const float* __restrict__ Cm,
                                              float* __restrict__ ws) {
  __shared__ __align__(16) float sh[13440];   // 53.8 KB
  float* Ilds = sh;            // [64][65] Minv
  float* Pa   = sh + 4352;     // [64][68]; aliases bs (Bt stage) and cs (C^T)
  float* Pb   = sh + 8704;     // [64][68]
  float* rbM  = sh + 13056;    // [2][64]
  float* rbI  = sh + 13184;    // [2][64]
  float* cb   = sh + 13312;    // [2][64]
  float* bs   = Pa;
  float* cs   = Pa;

  const int t  = threadIdx.x;
  const int tc = t & 63;
  const int tr = t >> 6;       // 0..3; owns rows 16*tr+i

  float M[16], Iv[16];
  for (int i = 0; i < 16; ++i) {
    int r = 16 * tr + i;
    M[i] = 0.05f * A[r * 64 + tc] + (r == tc ? 1.0f : 0.0f);
    Iv[i] = (r == tc) ? 1.0f : 0.0f;
  }
  if (tr == 0) { rbM[tc] = M[0]; rbI[tc] = Iv[0]; }
  if (tc == 0)
    for (int i = 0; i < 16; ++i) cb[16 * tr + i] = M[i];
  __syncthreads();

  // ---- Gauss-Jordan, no pivoting, 1 barrier/iter ----
#pragma unroll
  for (int k = 0; k < 64; ++k) {
    const int cur = (k & 1) * 64, nxt = ((k + 1) & 1) * 64;
    float rinv = 1.0f / rbM[cur + k];
    float rM = rbM[cur + tc] * rinv;
    float rI = rbI[cur + tc] * rinv;
#pragma unroll
    for (int i = 0; i < 16; ++i) {
      int r = 16 * tr + i;
      if (r == k) { M[i] = rM; Iv[i] = rI; }
      else {
        float f = cb[cur + r];
        M[i] = fmaf(-f, rM, M[i]);
        Iv[i] = fmaf(-f, rI, Iv[i]);
      }
    }
    if (k < 63) {
      if (tr == ((k + 1) >> 4)) {
        rbM[nxt + tc] = M[(k + 1) & 15];
        rbI[nxt + tc] = Iv[(k + 1) & 15];
      }
      if (tc == k + 1)
        for (int i = 0; i < 16; ++i) cb[nxt + 16 * tr + i] = M[i];
    }
    __syncthreads();
  }

  // ---- At = 2*Minv - I to global; Minv into Ilds ----
  for (int i = 0; i < 16; ++i) {
    int r = 16 * tr + i;
    ws[OFF_AT + r * 64 + tc] = 2.0f * Iv[i] - (r == tc ? 1.0f : 0.0f);
    Ilds[r * 65 + tc] = Iv[i];
  }
  __syncthreads();

  // ---- BTt[d][n] = 0.1 * sum_k Minv[n][k] * B[k][d], 4 rounds of 64 d ----
  {
    const int n = tc, g = tr;   // g wave-uniform -> bs reads broadcast
    for (int rd = 0; rd < 4; ++rd) {
      int d0 = rd * 64;
      for (int i = 0; i < 4; ++i) {
        int e = 4 * (t + 256 * i);            // 0..4092
        int kk = e >> 6, dd = e & 63;
        *(float4*)(bs + kk * 68 + dd) =
            *(const float4*)(Bm + kk * 256 + d0 + dd);
      }
      __syncthreads();
      float acc[16] = {};
      for (int k = 0; k < 64; ++k) {
        float av = Ilds[n * 65 + k];          // (n+k)%32 -> 2-way, free
#pragma unroll
        for (int j = 0; j < 16; ++j)
          acc[j] = fmaf(av, bs[k * 68 + g * 16 + j], acc[j]);
      }
      for (int j = 0; j < 16; ++j)
        ws[OFF_BT + (d0 + g * 16 + j) * 64 + n] = 0.1f * acc[j];
      __syncthreads();
    }
  }

  // ---- Pa = At; 6 squarings -> A64 ----
  for (int i = 0; i < 16; ++i) {
    int idx = t + 256 * i;                    // 0..4095
    int r = idx >> 6, c = idx & 63;
    Pa[r * 68 + c] = 2.0f * Ilds[r * 65 + c] - (r == c ? 1.0f : 0.0f);
  }
  __syncthreads();
  {
    float* src = Pa; float* dst = Pb;
    const int r0 = 4 * (t >> 4), c0 = 4 * (t & 15);
    for (int it = 0; it < 6; ++it) {
      float acc[4][4] = {};
      for (int k = 0; k < 64; ++k) {
        float4 bv = *(const float4*)(src + k * 68 + c0);
        for (int i = 0; i < 4; ++i) {
          float av = src[(r0 + i) * 68 + k];
          acc[i][0] = fmaf(av, bv.x, acc[i][0]);
          acc[i][1] = fmaf(av, bv.y, acc[i][1]);
          acc[i][2] = fmaf(av, bv.z, acc[i][2]);
          acc[i][3] = fmaf(av, bv.w, acc[i][3]);
        }
      }
      for (int i = 0; i < 4; ++i)
        *(float4*)(dst + (r0 + i) * 68 + c0) =
            make_float4(acc[i][0], acc[i][1], acc[i][2], acc[i][3]);
      __syncthreads();
      float* tmp = src; src = dst; dst = tmp;
    }
    for (int i = 0; i < 4; ++i) {
      int f = 4 * (t + 256 * i);
      int r = f >> 6, c = f & 63;
      *(float4*)(ws + OFF_A64 + f) = *(const float4*)(src + r * 68 + c);
    }
  }
  __syncthreads();

  // ---- CT[n][o] = C[o][n], via LDS pad-65 (scalar, 2-way free) ----
  for (int ob = 0; ob < 4; ++ob) {
    int o0 = ob * 64;
    for (int i = 0; i < 16; ++i) {
      int idx = t + 256 * i;                  // 0..4095
      int oo = idx >> 6, nn = idx & 63;
      cs[oo * 65 + nn] = Cm[(size_t)(o0 + oo) * 64 + nn];
    }
    __syncthreads();
    for (int i = 0; i < 16; ++i) {
      int idx = t + 256 * i;
      int nn = idx >> 6, oo = idx & 63;
      ws[OFF_CT + nn * 256 + o0 + oo] = cs[oo * 65 + nn];
    }
    __syncthreads();
  }
}

// ---------------------------------------------------------------------------
// K2: u[row][n] = sum_d x[row][d] * BTt[d][n]   (64-row tile, K=256)
// xs natural (reads broadcast), bs natural (reads b128 stride-1). 0 conflicts.
// ---------------------------------------------------------------------------
__global__ __launch_bounds__(256) void k_ugemm(const float* __restrict__ x,
                                               float* __restrict__ ws) {
  __shared__ __align__(16) float xs[64 * 68];
  __shared__ __align__(16) float bs[64 * 68];
  const float* Bt = ws + OFF_BT;
  float* u = ws + OFF_U;
  const int t = threadIdx.x;
  const int rowbase = blockIdx.x * 64;
  const int r0 = 4 * (t >> 4), n0 = 4 * (t & 15);
  float acc[4][4] = {};
  for (int db = 0; db < 4; ++db) {
    int d0 = db * 64;
    for (int i = 0; i < 4; ++i) {
      int e = 4 * (t + 256 * i);              // 0..4092
      int rr = e >> 6, dd = e & 63;
      *(float4*)(xs + rr * 68 + dd) =
          *(const float4*)(x + (size_t)(rowbase + rr) * 256 + d0 + dd);
      *(float4*)(bs + rr * 68 + dd) = *(const float4*)(Bt + d0 * 64 + e);
    }
    __syncthreads();
    for (int k = 0; k < 64; ++k) {
      float4 bv4 = *(const float4*)(bs + k * 68 + n0);
      for (int i = 0; i < 4; ++i) {
        float av = xs[(r0 + i) * 68 + k];     // broadcast
        acc[i][0] = fmaf(av, bv4.x, acc[i][0]);
        acc[i][1] = fmaf(av, bv4.y, acc[i][1]);
        acc[i][2] = fmaf(av, bv4.z, acc[i][2]);
        acc[i][3] = fmaf(av, bv4.w, acc[i][3]);
      }
    }
    __syncthreads();
  }
  for (int i = 0; i < 4; ++i)
    *(float4*)(u + (size_t)(rowbase + r0 + i) * 64 + n0) =
        make_float4(acc[i][0], acc[i][1], acc[i][2], acc[i][3]);
}

// ---------------------------------------------------------------------------
// Wave-level matvec: lane r holds row r of M (64 VGPRs) and h[r].
// Broadcast h[m] via v_readlane; no LDS, no barriers.
// ---------------------------------------------------------------------------
__device__ __forceinline__ float bcast(float v, int lane) {
  return __int_as_float(__builtin_amdgcn_readlane(__float_as_int(v), lane));
}

__device__ __forceinline__ float wave_matvec(const float areg[64], float h) {
  float a0 = 0.f, a1 = 0.f, a2 = 0.f, a3 = 0.f;
#pragma unroll
  for (int m = 0; m < 16; ++m) {
    a0 = fmaf(areg[m], bcast(h, m), a0);
    a1 = fmaf(areg[m + 16], bcast(h, m + 16), a1);
    a2 = fmaf(areg[m + 32], bcast(h, m + 32), a2);
    a3 = fmaf(areg[m + 48], bcast(h, m + 48), a3);
  }
  return (a0 + a1) + (a2 + a3);
}

__device__ __forceinline__ void load_arow(const float* __restrict__ M, int r,
                                          float areg[64]) {
#pragma unroll
  for (int i = 0; i < 16; ++i)
    *(float4*)(areg + 4 * i) = *(const float4*)(M + r * 64 + 4 * i);
}

// ---------------------------------------------------------------------------
// K3/K5: chunk scan, one wave per chunk (4 chunks/block).
// phase=1: h0=0, emit final state to S. phase=2: h0=S[b][c-1] (carry-fixed),
// emit every h to H.
// ---------------------------------------------------------------------------
__global__ __launch_bounds__(256) void k_chunk(float* __restrict__ ws, int phase) {
  const int t = threadIdx.x;
  const int r = t & 63, wid = t >> 6;
  const int c = blockIdx.x * 4 + wid, b = blockIdx.y;
  float areg[64];
  load_arow(ws + OFF_AT, r, areg);
  const float* uptr = ws + OFF_U + (size_t)(b * LEN + c * CHUNK) * 64;
  float* Hout = ws + OFF_H + (size_t)(b * LEN + c * CHUNK) * 64;
  float h = 0.f;
  if (phase == 2 && c > 0) h = ws[OFF_S + (b * NCHUNK + c - 1) * 64 + r];
  float ucur = uptr[r];
#pragma unroll 1
  for (int st = 0; st < CHUNK; ++st) {
    float unxt = (st + 1 < CHUNK) ? uptr[(st + 1) * 64 + r] : 0.f;
    h = wave_matvec(areg, h) + ucur;
    if (phase == 2) Hout[st * 64 + r] = h;
    ucur = unxt;
  }
  if (phase == 1) ws[OFF_S + (b * NCHUNK + c) * 64 + r] = h;
}

// ---------------------------------------------------------------------------
// K4: carry combine, one wave per batch b (in-place on S):
// S[b][c-1] <- carry_in(chunk c) = A64 @ carry_in(c-1) + S_local[b][c-1]
// ---------------------------------------------------------------------------
__global__ __launch_bounds__(64) void k_carry(float* __restrict__ ws) {
  const int r = threadIdx.x;
  const int b = blockIdx.x;
  float areg[64];
  load_arow(ws + OFF_A64, r, areg);
  float* S = ws + OFF_S + b * NCHUNK * 64;
  float h = 0.f;
#pragma unroll 1
  for (int c = 1; c < NCHUNK; ++c) {
    float sv = S[(c - 1) * 64 + r];
    h = wave_matvec(areg, h) + sv;
    S[(c - 1) * 64 + r] = h;
  }
}

// ---------------------------------------------------------------------------
// K6: y[row][o] = sum_n h[row][n] * CT[n][o]   (64-row tile, 4 o-blocks)
// ---------------------------------------------------------------------------
__global__ __launch_bounds__(256) void k_ygemm(float* __restrict__ ws,
                                               float* __restrict__ y) {
  __shared__ __align__(16) float hs[64 * 68];
  __shared__ __align__(16) float ct[64 * 68];
  const int t = threadIdx.x;
  const int rowbase = blockIdx.x * 64;
  const float* H = ws + OFF_H;
  const float* CT = ws + OFF_CT;
  for (int i = 0; i < 4; ++i) {
    int e = 4 * (t + 256 * i);
    int rr = e >> 6, nn = e & 63;
    *(float4*)(hs + rr * 68 + nn) =
        *(const float4*)(H + (size_t)rowbase * 64 + e);
  }
  const int r0 = 4 * (t >> 4), c0 = 4 * (t & 15);
  for (int ob = 0; ob < 4; ++ob) {
    int o0 = ob * 64;
    __syncthreads();
    for (int i = 0; i < 4; ++i) {
      int e = 4 * (t + 256 * i);
      int nn = e >> 6, oo = e & 63;
      *(float4*)(ct + nn * 68 + oo) = *(const float4*)(CT + nn * 256 + o0 + oo);
    }
    __syncthreads();
    float acc[4][4] = {};
    for (int k = 0; k < 64; ++k) {
      float4 cv4 = *(const float4*)(ct + k * 68 + c0);
      for (int i = 0; i < 4; ++i) {
        float hv = hs[(r0 + i) * 68 + k];     // broadcast
        acc[i][0] = fmaf(hv, cv4.x, acc[i][0]);
        acc[i][1] = fmaf(hv, cv4.y, acc[i][1]);
        acc[i][2] = fmaf(hv, cv4.z, acc[i][2]);
        acc[i][3] = fmaf(hv, cv4.w, acc[i][3]);
      }
    }
    for (int i = 0; i < 4; ++i)
      *(float4*)(y + (size_t)(rowbase + r0 + i) * 256 + o0 + c0) =
          make_float4(acc[i][0], acc[i][1], acc[i][2], acc[i][3]);
  }
}

// ---------------------------------------------------------------------------
extern "C" void kernel_launch(void* const* d_in, const int* in_sizes, int n_in,
                              void* d_out, int out_size, void* d_ws,
                              size_t ws_size, hipStream_t stream) {
  const float* x = (const float*)d_in[0];
  const float* A = (const float*)d_in[1];
  const float* Bm = (const float*)d_in[2];
  const float* Cm = (const float*)d_in[3];
  float* y = (float*)d_out;
  float* ws = (float*)d_ws;
  if (ws_size < (size_t)WS_FLOATS * sizeof(float)) return;

  hipLaunchKernelGGL(k_prep, dim3(1), dim3(256), 0, stream, A, Bm, Cm, ws);
  hipLaunchKernelGGL(k_ugemm, dim3(ROWS / 64), dim3(256), 0, stream, x, ws);
  hipLaunchKernelGGL(k_chunk, dim3(NCHUNK / 4, B_SZ), dim3(256), 0, stream, ws, 1);
  hipLaunchKernelGGL(k_carry, dim3(B_SZ), dim3(64), 0, stream, ws);
  hipLaunchKernelGGL(k_chunk, dim3(NCHUNK / 4, B_SZ), dim3(256), 0, stream, ws, 2);
  hipLaunchKernelGGL(k_ygemm, dim3(ROWS / 64), dim3(256), 0, stream, ws, y);
}